// Round 1
// baseline (86.749 us; speedup 1.0000x reference)
//
#include <hip/hip_runtime.h>
#include <math.h>

// Problem constants (match reference)
#define BB   16
#define CC   64
#define LL   512
#define LP   16
#define DM   1024
#define NP   64
#define PRD  256   // period = L/2
#define HEAD 128   // PRD/2
#define NV   256   // L - PRD

// ---------------------------------------------------------------------------
// Kernel A: per-(b,l) channel stats.  meanp[b,l] = mean_c / sqrt(var_c (ddof=1))
// ---------------------------------------------------------------------------
__global__ __launch_bounds__(256) void stats_kernel(
    const float* __restrict__ dx, float* __restrict__ meanp)
{
    int id = blockIdx.x * 256 + threadIdx.x;   // 0 .. B*L-1 = 8191
    if (id >= BB * LL) return;
    int b = id >> 9;          // / 512
    int l = id & 511;
    const float* p = dx + (size_t)b * CC * LL + l;
    float s = 0.f, sq = 0.f;
#pragma unroll 8
    for (int c = 0; c < CC; ++c) {
        float v = p[(size_t)c * LL];
        s  += v;
        sq += v * v;
    }
    float mean = s * (1.0f / CC);
    float var  = (sq - (float)CC * mean * mean) * (1.0f / (CC - 1));
    meanp[id] = mean / sqrtf(var);
}

// ---------------------------------------------------------------------------
// Kernel B: one block per (b,c) series. Transform -> decompose -> features ->
// 48x1024 matvec -> broadcast-write 64 identical patch rows.
// ---------------------------------------------------------------------------
__global__ __launch_bounds__(256) void series_kernel(
    const float* __restrict__ dx,    const float* __restrict__ gamma,
    const float* __restrict__ beta,  const float* __restrict__ meanp,
    const float* __restrict__ w_t,   const float* __restrict__ b_t,
    const float* __restrict__ w_s,   const float* __restrict__ b_s,
    const float* __restrict__ w_r,   const float* __restrict__ b_r,
    const float* __restrict__ w_g,   const float* __restrict__ b_g,
    float* __restrict__ out)
{
    __shared__ float xs[LL];      // transformed series
    __shared__ float tvs[NV];     // trend (valid part)
    __shared__ float pas[PRD];    // demeaned period averages (= seasonal pattern)
    __shared__ float feats[48];   // [t(16) | s(16) | r(16)]
    __shared__ float wred[4];     // per-wave partials

    const int tid = threadIdx.x;            // 0..255
    const int bc  = blockIdx.x;             // 0..1023  (= b*64 + c)
    const int b   = bc >> 6;

    // ---- load + per-channel "transform": x = gamma*(dx - mean/sqrt(var)) + beta
    const size_t base = (size_t)bc * LL;
#pragma unroll
    for (int l = tid; l < LL; l += 256) {
        float v = dx[base + l];
        float m = meanp[b * LL + l];
        xs[l] = gamma[base + l] * (v - m) + beta[base + l];
    }
    __syncthreads();

    // ---- centered moving average (257 taps, ends weighted 0.5), detrend
    const int i = tid;                       // 0..255 valid trend samples
    float s = 0.5f * (xs[i] + xs[i + 256]);
#pragma unroll 16
    for (int j = 1; j < 256; ++j) s += xs[i + j];
    const float tv = s * (1.0f / 256.0f);
    tvs[i] = tv;
    const float dv = xs[HEAD + i] - tv;      // detrended valid sample

    // ---- mdv = mean(dv) over 256 samples (wave reduce + cross-wave combine)
    float r = dv;
#pragma unroll
    for (int m = 32; m; m >>= 1) r += __shfl_xor(r, m, 64);
    if ((tid & 63) == 0) wred[tid >> 6] = r;
    __syncthreads();
    const float mdv = (wred[0] + wred[1] + wred[2] + wred[3]) * (1.0f / 256.0f);

    // pa[(i+128)%256] = dv[i] - mdv   (each phase occurs exactly once)
    pas[(i + 128) & 255] = dv - mdv;
    __syncthreads();

    // ---- feature dot products: 16 outputs each for trend/seasonal/resid.
    // resid is the constant mdv on [128,384) -> r[k] = mdv * sum(w_r[k,128:384]).
    {
        const int g  = tid >> 4;             // 0..15 : which output k
        const int ln = tid & 15;             // 16 lanes cooperate per k
        const float* wt  = w_t + g * LL + HEAD;
        const float* wsn = w_s + g * LL;
        const float* wr  = w_r + g * LL + HEAD;
        float at = 0.f, as = 0.f, ar = 0.f;
#pragma unroll 4
        for (int m = ln; m < 256; m += 16) {
            at += tvs[m] * wt[m];
            as += pas[m] * (wsn[m] + wsn[m + 256]);  // seasonal has period 256
            ar += wr[m];
        }
#pragma unroll
        for (int msk = 8; msk; msk >>= 1) {
            at += __shfl_xor(at, msk, 64);
            as += __shfl_xor(as, msk, 64);
            ar += __shfl_xor(ar, msk, 64);
        }
        if (ln == 0) {
            feats[g]      = at + b_t[g];
            feats[16 + g] = as + b_s[g];
            feats[32 + g] = mdv * ar + b_r[g];
        }
    }
    __syncthreads();

    // ---- g[d] = feats . w_g[d,:] + b_g[d], 4 consecutive d per thread
    float fr[48];
#pragma unroll
    for (int j = 0; j < 48; ++j) fr[j] = feats[j];

    const int d0 = tid * 4;
    float a[4];
#pragma unroll
    for (int row = 0; row < 4; ++row) {
        const float4* w4 = (const float4*)(w_g + (size_t)(d0 + row) * 48);
        float acc = b_g[d0 + row];
#pragma unroll
        for (int q = 0; q < 12; ++q) {
            float4 w = w4[q];
            acc += w.x * fr[q * 4 + 0] + w.y * fr[q * 4 + 1]
                 + w.z * fr[q * 4 + 2] + w.w * fr[q * 4 + 3];
        }
        a[row] = acc;
    }
    const float4 res = make_float4(a[0], a[1], a[2], a[3]);

    // ---- broadcast write: out[b,c,n,:] identical for all n (pure broadcast)
    float4* op = (float4*)out + (size_t)bc * (NP * DM / 4) + tid;
#pragma unroll 4
    for (int n = 0; n < NP; ++n)
        op[(size_t)n * (DM / 4)] = res;
}

// ---------------------------------------------------------------------------
extern "C" void kernel_launch(void* const* d_in, const int* in_sizes, int n_in,
                              void* d_out, int out_size, void* d_ws, size_t ws_size,
                              hipStream_t stream) {
    const float* dx    = (const float*)d_in[0];
    const float* gamma = (const float*)d_in[1];
    const float* beta  = (const float*)d_in[2];
    const float* w_t   = (const float*)d_in[3];
    const float* b_t   = (const float*)d_in[4];
    const float* w_s   = (const float*)d_in[5];
    const float* b_s   = (const float*)d_in[6];
    const float* w_r   = (const float*)d_in[7];
    const float* b_r   = (const float*)d_in[8];
    const float* w_g   = (const float*)d_in[9];
    const float* b_g   = (const float*)d_in[10];
    float* out = (float*)d_out;
    float* meanp = (float*)d_ws;               // B*L = 8192 floats

    stats_kernel<<<(BB * LL + 255) / 256, 256, 0, stream>>>(dx, meanp);
    series_kernel<<<BB * CC, 256, 0, stream>>>(
        dx, gamma, beta, meanp,
        w_t, b_t, w_s, b_s, w_r, b_r, w_g, b_g, out);
}

// Round 3
// 84.896 us; speedup vs baseline: 1.0218x; 1.0218x over previous
//
#include <hip/hip_runtime.h>
#include <math.h>

// Problem constants (match reference)
#define BB   16
#define CC   64
#define LL   512
#define LP   16
#define DM   1024
#define NP   64
#define PRD  256   // period = L/2
#define HEAD 128   // PRD/2
#define NV   256   // L - PRD

typedef float f32x4 __attribute__((ext_vector_type(4)));

// ---------------------------------------------------------------------------
// Kernel A: per-(b,l) channel stats.  meanp[b,l] = mean_c / sqrt(var_c (ddof=1))
// ---------------------------------------------------------------------------
__global__ __launch_bounds__(128) void stats_kernel(
    const float* __restrict__ dx, float* __restrict__ meanp)
{
    int id = blockIdx.x * 128 + threadIdx.x;   // 0 .. B*L-1 = 8191
    if (id >= BB * LL) return;
    int b = id >> 9;          // / 512
    int l = id & 511;
    const float* p = dx + (size_t)b * CC * LL + l;
    float s = 0.f, sq = 0.f;
#pragma unroll 8
    for (int c = 0; c < CC; ++c) {
        float v = p[(size_t)c * LL];
        s  += v;
        sq += v * v;
    }
    float mean = s * (1.0f / CC);
    float var  = (sq - (float)CC * mean * mean) * (1.0f / (CC - 1));
    meanp[id] = mean / sqrtf(var);
}

// ---------------------------------------------------------------------------
// Kernel B: one block per (b,c) series. Transform -> scan-based decompose ->
// features -> 48x1024 matvec -> broadcast-write 64 identical patch rows.
// ---------------------------------------------------------------------------
__global__ __launch_bounds__(256) void series_kernel(
    const float* __restrict__ dx,    const float* __restrict__ gamma,
    const float* __restrict__ beta,  const float* __restrict__ meanp,
    const float* __restrict__ w_t,   const float* __restrict__ b_t,
    const float* __restrict__ w_s,   const float* __restrict__ b_s,
    const float* __restrict__ w_r,   const float* __restrict__ b_r,
    const float* __restrict__ w_g,   const float* __restrict__ b_g,
    float* __restrict__ out)
{
    __shared__ __align__(16) float xs[LL];     // transformed series
    __shared__ __align__(16) float pps[LL/2 + 1]; // inclusive pair-prefix sums (+lead 0)
    __shared__ __align__(16) float tvs[NV];    // trend (valid part)
    __shared__ __align__(16) float pas[PRD];   // demeaned period averages
    __shared__ __align__(16) float feats[48];  // [t(16) | s(16) | r(16)]
    __shared__ float wsum[4];                  // per-wave scan totals
    __shared__ float wred[4];                  // per-wave reduce partials

    const int tid  = threadIdx.x;              // 0..255
    const int lane = tid & 63;
    const int wv   = tid >> 6;
    const int bc   = blockIdx.x;               // 0..1023  (= b*64 + c)
    const int b    = bc >> 6;

    // ---- load + transform (float2 vectorized): x = gamma*(dx - meanp) + beta
    const size_t base = (size_t)bc * LL;
    float2 xv = ((const float2*)(dx    + base))[tid];
    float2 gv = ((const float2*)(gamma + base))[tid];
    float2 bv = ((const float2*)(beta  + base))[tid];
    float2 mv = ((const float2*)(meanp + (size_t)b * LL))[tid];
    float2 xp;
    xp.x = gv.x * (xv.x - mv.x) + bv.x;
    xp.y = gv.y * (xv.y - mv.y) + bv.y;
    ((float2*)xs)[tid] = xp;

    // ---- inclusive scan of pair-sums across the block (256 pairs)
    float v = xp.x + xp.y;
#pragma unroll
    for (int d = 1; d < 64; d <<= 1) {
        float t = __shfl_up(v, d, 64);
        if (lane >= d) v += t;
    }
    if (lane == 63) wsum[wv] = v;
    __syncthreads();
    float off = 0.f;
    for (int w = 0; w < wv; ++w) off += wsum[w];
    pps[tid + 1] = v + off;                    // pps[m+1] = sum of first 2(m+1) elems
    if (tid == 0) pps[0] = 0.f;
    __syncthreads();

    // ---- trend: W[i] = P(i+257) - P(i) - 0.5*(xs[i]+xs[i+256]);  tv = W/256
    // P(k) = pps[k>>1] + (k odd ? xs[k-1] : 0)
    const int i  = tid;
    const int k2 = i + 257;
    const float Pi = pps[i  >> 1] + ((i  & 1) ? xs[i  & ~1] : 0.f);
    const float Pk = pps[k2 >> 1] + ((k2 & 1) ? xs[k2 & ~1] : 0.f);
    const float x_i   = xs[i];
    const float x_i2  = xs[i + 256];
    const float tv = (Pk - Pi - 0.5f * (x_i + x_i2)) * (1.0f / 256.0f);
    tvs[i] = tv;
    const float dv = xs[HEAD + i] - tv;        // detrended valid sample

    // ---- mdv = mean(dv) over 256 samples
    float r = dv;
#pragma unroll
    for (int m = 32; m; m >>= 1) r += __shfl_xor(r, m, 64);
    if (lane == 0) wred[wv] = r;
    __syncthreads();
    const float mdv = (wred[0] + wred[1] + wred[2] + wred[3]) * (1.0f / 256.0f);

    // pa[(i+128)%256] = dv - mdv   (each phase occurs exactly once; nvalid == p)
    pas[(i + 128) & 255] = dv - mdv;
    __syncthreads();

    // ---- feature dot products (float4-chunked; 16 lanes cooperate per output)
    // resid is the constant mdv on [128,384): r[k] = mdv * sum(w_r[k,128:384]).
    {
        const int g  = tid >> 4;               // 0..15 : which output k
        const int ln = tid & 15;
        const float4* wt4  = (const float4*)(w_t + g * LL + HEAD);
        const float4* ws4a = (const float4*)(w_s + g * LL);
        const float4* ws4b = (const float4*)(w_s + g * LL + 256);
        const float4* wr4  = (const float4*)(w_r + g * LL + HEAD);
        const float4* tv4  = (const float4*)tvs;
        const float4* pa4  = (const float4*)pas;
        float at = 0.f, as = 0.f, ar = 0.f;
#pragma unroll
        for (int q = 0; q < 4; ++q) {
            const int m = ln * 4 + q;           // float4 index 0..63
            float4 t  = tv4[m],  p  = pa4[m];
            float4 a  = wt4[m];
            float4 s1 = ws4a[m], s2 = ws4b[m];
            float4 rr = wr4[m];
            at += t.x * a.x + t.y * a.y + t.z * a.z + t.w * a.w;
            as += p.x * (s1.x + s2.x) + p.y * (s1.y + s2.y)
                + p.z * (s1.z + s2.z) + p.w * (s1.w + s2.w);
            ar += rr.x + rr.y + rr.z + rr.w;
        }
#pragma unroll
        for (int msk = 8; msk; msk >>= 1) {
            at += __shfl_xor(at, msk, 64);
            as += __shfl_xor(as, msk, 64);
            ar += __shfl_xor(ar, msk, 64);
        }
        if (ln == 0) {
            feats[g]      = at + b_t[g];
            feats[16 + g] = as + b_s[g];
            feats[32 + g] = mdv * ar + b_r[g];
        }
    }
    __syncthreads();

    // ---- g[d] = feats . w_g[d,:] + b_g[d], 4 consecutive d per thread
    float fr[48];
#pragma unroll
    for (int j = 0; j < 48; ++j) fr[j] = feats[j];

    const int d0 = tid * 4;
    float a[4];
#pragma unroll
    for (int row = 0; row < 4; ++row) {
        const float4* w4 = (const float4*)(w_g + (size_t)(d0 + row) * 48);
        float acc = b_g[d0 + row];
#pragma unroll
        for (int q = 0; q < 12; ++q) {
            float4 w = w4[q];
            acc += w.x * fr[q * 4 + 0] + w.y * fr[q * 4 + 1]
                 + w.z * fr[q * 4 + 2] + w.w * fr[q * 4 + 3];
        }
        a[row] = acc;
    }
    f32x4 res;
    res.x = a[0]; res.y = a[1]; res.z = a[2]; res.w = a[3];

    // ---- broadcast write: out[b,c,n,:] identical for all n (pure broadcast).
    // Streaming 256 MiB, never re-read -> non-temporal stores.
    f32x4* op = (f32x4*)out + (size_t)bc * (NP * DM / 4) + tid;
#pragma unroll 4
    for (int n = 0; n < NP; ++n)
        __builtin_nontemporal_store(res, op + (size_t)n * (DM / 4));
}

// ---------------------------------------------------------------------------
extern "C" void kernel_launch(void* const* d_in, const int* in_sizes, int n_in,
                              void* d_out, int out_size, void* d_ws, size_t ws_size,
                              hipStream_t stream) {
    const float* dx    = (const float*)d_in[0];
    const float* gamma = (const float*)d_in[1];
    const float* beta  = (const float*)d_in[2];
    const float* w_t   = (const float*)d_in[3];
    const float* b_t   = (const float*)d_in[4];
    const float* w_s   = (const float*)d_in[5];
    const float* b_s   = (const float*)d_in[6];
    const float* w_r   = (const float*)d_in[7];
    const float* b_r   = (const float*)d_in[8];
    const float* w_g   = (const float*)d_in[9];
    const float* b_g   = (const float*)d_in[10];
    float* out = (float*)d_out;
    float* meanp = (float*)d_ws;               // B*L = 8192 floats

    stats_kernel<<<(BB * LL + 127) / 128, 128, 0, stream>>>(dx, meanp);
    series_kernel<<<BB * CC, 256, 0, stream>>>(
        dx, gamma, beta, meanp,
        w_t, b_t, w_s, b_s, w_r, b_r, w_g, b_g, out);
}